// Round 1
// baseline (618.774 us; speedup 1.0000x reference)
//
#include <hip/hip_runtime.h>
#include <math.h>

#define NBOX 1024
#define ROI_N 7
#define CH 32
#define FEAT (ROI_N*ROI_N*CH)   // 1568
#define HD 2048
#define NMS_THR_F 0.01f
#define NMS_OUT 100

// ---------------- ROI align (both maps) + fuse ----------------
__global__ __launch_bounds__(256) void roi_fuse_kernel(
    const float* __restrict__ img, const float* __restrict__ bev,
    const float* __restrict__ img_boxes, const float* __restrict__ bev_boxes,
    const float* __restrict__ img_mask, const float* __restrict__ bev_mask,
    float* __restrict__ xout)
{
  const int b = blockIdx.x;
  const float mi = img_mask[0], mb = bev_mask[0];
  const float denom = mi + mb;

  const float iy0 = img_boxes[b*4+0], ix0 = img_boxes[b*4+1];
  const float iy1 = img_boxes[b*4+2], ix1 = img_boxes[b*4+3];
  const float by0 = bev_boxes[b*4+0], bx0 = bev_boxes[b*4+1];
  const float by1 = bev_boxes[b*4+2], bx1 = bev_boxes[b*4+3];

  for (int idx = threadIdx.x; idx < FEAT; idx += 256) {
    const int ti  = idx / (ROI_N*CH);
    const int rem = idx - ti*(ROI_N*CH);
    const int tj  = rem >> 5;
    const int c   = rem & 31;
    const float tt_i = (ti == ROI_N-1) ? 1.0f : ti * (1.0f/(ROI_N-1));
    const float tt_j = (tj == ROI_N-1) ? 1.0f : tj * (1.0f/(ROI_N-1));

    float vi, vb;
    {
      const int H = 360, W = 1200;
      const float ys = (iy0 + (iy1 - iy0) * tt_i) * (float)(H-1);
      const float xs = (ix0 + (ix1 - ix0) * tt_j) * (float)(W-1);
      int y0 = (int)floorf(ys); y0 = y0 < 0 ? 0 : (y0 > H-1 ? H-1 : y0);
      int x0 = (int)floorf(xs); x0 = x0 < 0 ? 0 : (x0 > W-1 ? W-1 : x0);
      const int y1 = (y0+1 > H-1) ? H-1 : y0+1;
      const int x1 = (x0+1 > W-1) ? W-1 : x0+1;
      const float wy = ys - (float)y0;
      const float wx = xs - (float)x0;
      const float f00 = img[(y0*W + x0)*CH + c];
      const float f01 = img[(y0*W + x1)*CH + c];
      const float f10 = img[(y1*W + x0)*CH + c];
      const float f11 = img[(y1*W + x1)*CH + c];
      vi = f00*(1.0f-wy)*(1.0f-wx) + f01*(1.0f-wy)*wx
         + f10*wy*(1.0f-wx)        + f11*wy*wx;
    }
    {
      const int H = 700, W = 800;
      const float ys = (by0 + (by1 - by0) * tt_i) * (float)(H-1);
      const float xs = (bx0 + (bx1 - bx0) * tt_j) * (float)(W-1);
      int y0 = (int)floorf(ys); y0 = y0 < 0 ? 0 : (y0 > H-1 ? H-1 : y0);
      int x0 = (int)floorf(xs); x0 = x0 < 0 ? 0 : (x0 > W-1 ? W-1 : x0);
      const int y1 = (y0+1 > H-1) ? H-1 : y0+1;
      const int x1 = (x0+1 > W-1) ? W-1 : x0+1;
      const float wy = ys - (float)y0;
      const float wx = xs - (float)x0;
      const float f00 = bev[(y0*W + x0)*CH + c];
      const float f01 = bev[(y0*W + x1)*CH + c];
      const float f10 = bev[(y1*W + x0)*CH + c];
      const float f11 = bev[(y1*W + x1)*CH + c];
      vb = f00*(1.0f-wy)*(1.0f-wx) + f01*(1.0f-wy)*wx
         + f10*wy*(1.0f-wx)        + f11*wy*wx;
    }
    xout[(size_t)b*FEAT + idx] = (mi*vi + mb*vb) / denom;
  }
}

// ---------------- f32 tiled GEMM, fused bias (+ReLU) ----------------
// C[M,N] = act(A[M,K] @ B[K,N] + bias[N]); 64x64 tile, BK=16, 256 threads.
template<int RELU>
__global__ __launch_bounds__(256) void gemm_bias_act(
    const float* __restrict__ A, const float* __restrict__ B,
    const float* __restrict__ bias, float* __restrict__ C,
    int M, int N, int K)
{
  __shared__ float As[16][72];  // [k][m], row stride 72 floats (288B, 16B-aligned)
  __shared__ float Bs[16][64];  // [k][n]
  const int tid  = threadIdx.x;
  const int tx   = tid & 15;
  const int ty   = tid >> 4;
  const int row0 = blockIdx.y * 64;
  const int col0 = blockIdx.x * 64;
  const int arow = tid >> 2;
  const int acol = (tid & 3) * 4;
  const int brow = tid >> 4;
  const int bcol = (tid & 15) * 4;

  float acc[4][4];
#pragma unroll
  for (int i = 0; i < 4; ++i)
#pragma unroll
    for (int j = 0; j < 4; ++j) acc[i][j] = 0.0f;

  for (int k0 = 0; k0 < K; k0 += 16) {
    const float4 av = *(const float4*)&A[(size_t)(row0 + arow)*K + k0 + acol];
    const float4 bv = *(const float4*)&B[(size_t)(k0 + brow)*N + col0 + bcol];
    __syncthreads();
    As[acol+0][arow] = av.x;
    As[acol+1][arow] = av.y;
    As[acol+2][arow] = av.z;
    As[acol+3][arow] = av.w;
    *(float4*)&Bs[brow][bcol] = bv;
    __syncthreads();
#pragma unroll
    for (int kk = 0; kk < 16; ++kk) {
      const float4 a = *(const float4*)&As[kk][ty*4];
      const float4 b = *(const float4*)&Bs[kk][tx*4];
      acc[0][0] += a.x*b.x; acc[0][1] += a.x*b.y; acc[0][2] += a.x*b.z; acc[0][3] += a.x*b.w;
      acc[1][0] += a.y*b.x; acc[1][1] += a.y*b.y; acc[1][2] += a.y*b.z; acc[1][3] += a.y*b.w;
      acc[2][0] += a.z*b.x; acc[2][1] += a.z*b.y; acc[2][2] += a.z*b.z; acc[2][3] += a.z*b.w;
      acc[3][0] += a.w*b.x; acc[3][1] += a.w*b.y; acc[3][2] += a.w*b.z; acc[3][3] += a.w*b.w;
    }
  }
#pragma unroll
  for (int i = 0; i < 4; ++i) {
    const int r = row0 + ty*4 + i;
#pragma unroll
    for (int j = 0; j < 4; ++j) {
      const int cc = col0 + tx*4 + j;
      float v = acc[i][j] + bias[cc];
      if (RELU) v = fmaxf(v, 0.0f);
      C[(size_t)r*N + cc] = v;
    }
  }
}

// ---------------- heads: obj(2), off(10), ang(2) + postproc per row ----------------
__global__ __launch_bounds__(256) void heads_kernel(
    const float* __restrict__ h,
    const float* __restrict__ Wc, const float* __restrict__ bc,
    const float* __restrict__ Wo, const float* __restrict__ bo,
    const float* __restrict__ Wa, const float* __restrict__ ba,
    const float* __restrict__ bev_abs,
    float* __restrict__ obj_soft, float* __restrict__ boxes,
    float* __restrict__ orient, float* __restrict__ scores)
{
  const int r = blockIdx.x;
  const int tid = threadIdx.x;
  float acc[14];
#pragma unroll
  for (int j = 0; j < 14; ++j) acc[j] = 0.0f;
  for (int k = tid; k < HD; k += 256) {
    const float hv = h[(size_t)r*HD + k];
    acc[0]  += hv * Wc[k*2+0];
    acc[1]  += hv * Wc[k*2+1];
#pragma unroll
    for (int j = 0; j < 10; ++j) acc[2+j] += hv * Wo[k*10+j];
    acc[12] += hv * Wa[k*2+0];
    acc[13] += hv * Wa[k*2+1];
  }
  __shared__ float red[14][256];
#pragma unroll
  for (int j = 0; j < 14; ++j) red[j][tid] = acc[j];
  __syncthreads();
  for (int s = 128; s > 0; s >>= 1) {
    if (tid < s) {
#pragma unroll
      for (int j = 0; j < 14; ++j) red[j][tid] += red[j][tid + s];
    }
    __syncthreads();
  }
  if (tid == 0) {
    const float obj0 = red[0][0] + bc[0];
    const float obj1 = red[1][0] + bc[1];
    float off0 = red[2][0] + bo[0];
    float off1 = red[3][0] + bo[1];
    float off2 = red[4][0] + bo[2];
    float off3 = red[5][0] + bo[3];
    const float a0 = red[12][0] + ba[0];
    const float a1 = red[13][0] + ba[1];

    const float m  = fmaxf(obj0, obj1);
    const float e0 = expf(obj0 - m), e1 = expf(obj1 - m);
    const float se = e0 + e1;
    obj_soft[r*2+0] = e0 / se;
    obj_soft[r*2+1] = e1 / se;
    orient[r] = atan2f(a1, a0);

    const float pb0 = bev_abs[r*4+0] + 0.1f*off0;
    const float pb1 = bev_abs[r*4+1] + 0.1f*off1;
    const float pb2 = bev_abs[r*4+2] + 0.1f*off2;
    const float pb3 = bev_abs[r*4+3] + 0.1f*off3;
    boxes[r*4+0] = fminf(pb0, pb2);
    boxes[r*4+1] = fminf(pb1, pb3);
    boxes[r*4+2] = fmaxf(pb0, pb2);
    boxes[r*4+3] = fmaxf(pb1, pb3);
    scores[r] = obj1;   // max over obj[:,1:] with 2 cols == obj[:,1]
  }
}

// ---------------- NMS (exact reference semantics) + output gather ----------------
__global__ __launch_bounds__(1024) void nms_out_kernel(
    const float* __restrict__ boxes, const float* __restrict__ scores,
    const float* __restrict__ obj_soft, const float* __restrict__ orient,
    float* __restrict__ out)
{
  __shared__ float ss[NBOX];
  __shared__ int   order[NBOX];
  __shared__ float sb0[NBOX], sb1[NBOX], sb2[NBOX], sb3[NBOX], sarea[NBOX];
  __shared__ int   keep[NBOX];
  __shared__ int   total_keep;
  const int tid = threadIdx.x;

  ss[tid] = scores[tid];
  __syncthreads();

  // stable descending argsort by rank counting
  const float my = ss[tid];
  int pos = 0;
  for (int j = 0; j < NBOX; ++j) {
    const float sj = ss[j];
    pos += (sj > my) || (sj == my && j < tid);
  }
  order[pos] = tid;
  __syncthreads();

  const int ob = order[tid];
  const float b0 = boxes[ob*4+0], b1 = boxes[ob*4+1];
  const float b2 = boxes[ob*4+2], b3 = boxes[ob*4+3];
  sb0[tid]=b0; sb1[tid]=b1; sb2[tid]=b2; sb3[tid]=b3;
  const float area = fmaxf(b2-b0, 0.0f) * fmaxf(b3-b1, 0.0f);
  sarea[tid] = area;
  keep[tid] = 1;
  __syncthreads();

  // greedy suppression in sorted order
  for (int i = 0; i < NBOX-1; ++i) {
    if (keep[i]) {              // block-uniform branch (LDS broadcast)
      if (tid > i) {
        const float lt0 = fmaxf(sb0[i], b0);
        const float lt1 = fmaxf(sb1[i], b1);
        const float rb0 = fminf(sb2[i], b2);
        const float rb1 = fminf(sb3[i], b3);
        const float w = fmaxf(rb0 - lt0, 0.0f);
        const float h = fmaxf(rb1 - lt1, 0.0f);
        const float inter = w*h;
        const float iou = inter / (sarea[i] + area - inter + 1e-8f);
        if (iou > NMS_THR_F) keep[tid] = 0;
      }
    }
    __syncthreads();
  }

  // rank = kept (by sorted pos) first, then suppressed (by sorted pos)
  int kcnt = 0;
  for (int j = 0; j < tid; ++j) kcnt += keep[j];
  if (tid == NBOX-1) total_keep = kcnt + keep[tid];
  __syncthreads();
  const int rank = keep[tid] ? kcnt : (total_keep + tid - kcnt);

  if (rank < NMS_OUT) {
    out[rank*7+0] = obj_soft[ob*2+0];
    out[rank*7+1] = obj_soft[ob*2+1];
    out[rank*7+2] = b0;
    out[rank*7+3] = b1;
    out[rank*7+4] = b2;
    out[rank*7+5] = b3;
    out[rank*7+6] = orient[ob];
  }
}

extern "C" void kernel_launch(void* const* d_in, const int* in_sizes, int n_in,
                              void* d_out, int out_size, void* d_ws, size_t ws_size,
                              hipStream_t stream) {
  (void)in_sizes; (void)n_in; (void)out_size; (void)ws_size;
  const float* img       = (const float*)d_in[0];
  const float* bev       = (const float*)d_in[1];
  const float* img_boxes = (const float*)d_in[2];
  const float* bev_boxes = (const float*)d_in[3];
  const float* bev_abs   = (const float*)d_in[4];
  const float* img_mask  = (const float*)d_in[5];
  const float* bev_mask  = (const float*)d_in[6];
  const float* W1 = (const float*)d_in[7];
  const float* b1 = (const float*)d_in[8];
  const float* W2 = (const float*)d_in[9];
  const float* b2 = (const float*)d_in[10];
  const float* Wc = (const float*)d_in[11];
  const float* bc = (const float*)d_in[12];
  const float* Wo = (const float*)d_in[13];
  const float* bo = (const float*)d_in[14];
  const float* Wa = (const float*)d_in[15];
  const float* ba = (const float*)d_in[16];
  float* out = (float*)d_out;

  float* ws = (float*)d_ws;
  float* x        = ws;                       // 1024*1568
  float* h1       = x  + (size_t)NBOX*FEAT;   // 1024*2048
  float* h2       = h1 + (size_t)NBOX*HD;     // 1024*2048
  float* obj_soft = h2 + (size_t)NBOX*HD;     // 1024*2
  float* boxesf   = obj_soft + NBOX*2;        // 1024*4
  float* orient   = boxesf + NBOX*4;          // 1024
  float* scores   = orient + NBOX;            // 1024

  roi_fuse_kernel<<<NBOX, 256, 0, stream>>>(img, bev, img_boxes, bev_boxes,
                                            img_mask, bev_mask, x);
  gemm_bias_act<1><<<dim3(HD/64, NBOX/64), 256, 0, stream>>>(x,  W1, b1, h1, NBOX, HD, FEAT);
  gemm_bias_act<1><<<dim3(HD/64, NBOX/64), 256, 0, stream>>>(h1, W2, b2, h2, NBOX, HD, HD);
  heads_kernel<<<NBOX, 256, 0, stream>>>(h2, Wc, bc, Wo, bo, Wa, ba, bev_abs,
                                         obj_soft, boxesf, orient, scores);
  nms_out_kernel<<<1, 1024, 0, stream>>>(boxesf, scores, obj_soft, orient, out);
}

// Round 3
// 494.871 us; speedup vs baseline: 1.2504x; 1.2504x over previous
//
#include <hip/hip_runtime.h>
#include <math.h>

#define NBOX 1024
#define ROI_N 7
#define CH 32
#define FEAT (ROI_N*ROI_N*CH)   // 1568
#define HD 2048
#define NMS_THR_F 0.01f
#define NMS_OUT 100
#define MTRI_WORDS 8704         // sum_{b=0..15} 64*(16-b)

// ---------------- ROI align (both maps) + fuse ----------------
__global__ __launch_bounds__(256) void roi_fuse_kernel(
    const float* __restrict__ img, const float* __restrict__ bev,
    const float* __restrict__ img_boxes, const float* __restrict__ bev_boxes,
    const float* __restrict__ img_mask, const float* __restrict__ bev_mask,
    float* __restrict__ xout)
{
  const int b = blockIdx.x;
  const float mi = img_mask[0], mb = bev_mask[0];
  const float denom = mi + mb;

  const float iy0 = img_boxes[b*4+0], ix0 = img_boxes[b*4+1];
  const float iy1 = img_boxes[b*4+2], ix1 = img_boxes[b*4+3];
  const float by0 = bev_boxes[b*4+0], bx0 = bev_boxes[b*4+1];
  const float by1 = bev_boxes[b*4+2], bx1 = bev_boxes[b*4+3];

  for (int idx = threadIdx.x; idx < FEAT; idx += 256) {
    const int ti  = idx / (ROI_N*CH);
    const int rem = idx - ti*(ROI_N*CH);
    const int tj  = rem >> 5;
    const int c   = rem & 31;
    const float tt_i = (ti == ROI_N-1) ? 1.0f : ti * (1.0f/(ROI_N-1));
    const float tt_j = (tj == ROI_N-1) ? 1.0f : tj * (1.0f/(ROI_N-1));

    float vi, vb;
    {
      const int H = 360, W = 1200;
      const float ys = (iy0 + (iy1 - iy0) * tt_i) * (float)(H-1);
      const float xs = (ix0 + (ix1 - ix0) * tt_j) * (float)(W-1);
      int y0 = (int)floorf(ys); y0 = y0 < 0 ? 0 : (y0 > H-1 ? H-1 : y0);
      int x0 = (int)floorf(xs); x0 = x0 < 0 ? 0 : (x0 > W-1 ? W-1 : x0);
      const int y1 = (y0+1 > H-1) ? H-1 : y0+1;
      const int x1 = (x0+1 > W-1) ? W-1 : x0+1;
      const float wy = ys - (float)y0;
      const float wx = xs - (float)x0;
      const float f00 = img[(y0*W + x0)*CH + c];
      const float f01 = img[(y0*W + x1)*CH + c];
      const float f10 = img[(y1*W + x0)*CH + c];
      const float f11 = img[(y1*W + x1)*CH + c];
      vi = f00*(1.0f-wy)*(1.0f-wx) + f01*(1.0f-wy)*wx
         + f10*wy*(1.0f-wx)        + f11*wy*wx;
    }
    {
      const int H = 700, W = 800;
      const float ys = (by0 + (by1 - by0) * tt_i) * (float)(H-1);
      const float xs = (bx0 + (bx1 - bx0) * tt_j) * (float)(W-1);
      int y0 = (int)floorf(ys); y0 = y0 < 0 ? 0 : (y0 > H-1 ? H-1 : y0);
      int x0 = (int)floorf(xs); x0 = x0 < 0 ? 0 : (x0 > W-1 ? W-1 : x0);
      const int y1 = (y0+1 > H-1) ? H-1 : y0+1;
      const int x1 = (x0+1 > W-1) ? W-1 : x0+1;
      const float wy = ys - (float)y0;
      const float wx = xs - (float)x0;
      const float f00 = bev[(y0*W + x0)*CH + c];
      const float f01 = bev[(y0*W + x1)*CH + c];
      const float f10 = bev[(y1*W + x0)*CH + c];
      const float f11 = bev[(y1*W + x1)*CH + c];
      vb = f00*(1.0f-wy)*(1.0f-wx) + f01*(1.0f-wy)*wx
         + f10*wy*(1.0f-wx)        + f11*wy*wx;
    }
    xout[(size_t)b*FEAT + idx] = (mi*vi + mb*vb) / denom;
  }
}

// ---------------- f32 tiled GEMM, fused bias (+ReLU) ----------------
template<int RELU>
__global__ __launch_bounds__(256) void gemm_bias_act(
    const float* __restrict__ A, const float* __restrict__ B,
    const float* __restrict__ bias, float* __restrict__ C,
    int M, int N, int K)
{
  __shared__ float As[16][72];
  __shared__ float Bs[16][64];
  const int tid  = threadIdx.x;
  const int tx   = tid & 15;
  const int ty   = tid >> 4;
  const int row0 = blockIdx.y * 64;
  const int col0 = blockIdx.x * 64;
  const int arow = tid >> 2;
  const int acol = (tid & 3) * 4;
  const int brow = tid >> 4;
  const int bcol = (tid & 15) * 4;

  float acc[4][4];
#pragma unroll
  for (int i = 0; i < 4; ++i)
#pragma unroll
    for (int j = 0; j < 4; ++j) acc[i][j] = 0.0f;

  for (int k0 = 0; k0 < K; k0 += 16) {
    const float4 av = *(const float4*)&A[(size_t)(row0 + arow)*K + k0 + acol];
    const float4 bv = *(const float4*)&B[(size_t)(k0 + brow)*N + col0 + bcol];
    __syncthreads();
    As[acol+0][arow] = av.x;
    As[acol+1][arow] = av.y;
    As[acol+2][arow] = av.z;
    As[acol+3][arow] = av.w;
    *(float4*)&Bs[brow][bcol] = bv;
    __syncthreads();
#pragma unroll
    for (int kk = 0; kk < 16; ++kk) {
      const float4 a = *(const float4*)&As[kk][ty*4];
      const float4 b = *(const float4*)&Bs[kk][tx*4];
      acc[0][0] += a.x*b.x; acc[0][1] += a.x*b.y; acc[0][2] += a.x*b.z; acc[0][3] += a.x*b.w;
      acc[1][0] += a.y*b.x; acc[1][1] += a.y*b.y; acc[1][2] += a.y*b.z; acc[1][3] += a.y*b.w;
      acc[2][0] += a.z*b.x; acc[2][1] += a.z*b.y; acc[2][2] += a.z*b.z; acc[2][3] += a.z*b.w;
      acc[3][0] += a.w*b.x; acc[3][1] += a.w*b.y; acc[3][2] += a.w*b.z; acc[3][3] += a.w*b.w;
    }
  }
#pragma unroll
  for (int i = 0; i < 4; ++i) {
    const int r = row0 + ty*4 + i;
#pragma unroll
    for (int j = 0; j < 4; ++j) {
      const int cc = col0 + tx*4 + j;
      float v = acc[i][j] + bias[cc];
      if (RELU) v = fmaxf(v, 0.0f);
      C[(size_t)r*N + cc] = v;
    }
  }
}

// ---------------- heads ----------------
__global__ __launch_bounds__(256) void heads_kernel(
    const float* __restrict__ h,
    const float* __restrict__ Wc, const float* __restrict__ bc,
    const float* __restrict__ Wo, const float* __restrict__ bo,
    const float* __restrict__ Wa, const float* __restrict__ ba,
    const float* __restrict__ bev_abs,
    float* __restrict__ obj_soft, float* __restrict__ boxes,
    float* __restrict__ orient, float* __restrict__ scores)
{
  const int r = blockIdx.x;
  const int tid = threadIdx.x;
  float acc[14];
#pragma unroll
  for (int j = 0; j < 14; ++j) acc[j] = 0.0f;
  for (int k = tid; k < HD; k += 256) {
    const float hv = h[(size_t)r*HD + k];
    acc[0]  += hv * Wc[k*2+0];
    acc[1]  += hv * Wc[k*2+1];
#pragma unroll
    for (int j = 0; j < 10; ++j) acc[2+j] += hv * Wo[k*10+j];
    acc[12] += hv * Wa[k*2+0];
    acc[13] += hv * Wa[k*2+1];
  }
  __shared__ float red[14][256];
#pragma unroll
  for (int j = 0; j < 14; ++j) red[j][tid] = acc[j];
  __syncthreads();
  for (int s = 128; s > 0; s >>= 1) {
    if (tid < s) {
#pragma unroll
      for (int j = 0; j < 14; ++j) red[j][tid] += red[j][tid + s];
    }
    __syncthreads();
  }
  if (tid == 0) {
    const float obj0 = red[0][0] + bc[0];
    const float obj1 = red[1][0] + bc[1];
    float off0 = red[2][0] + bo[0];
    float off1 = red[3][0] + bo[1];
    float off2 = red[4][0] + bo[2];
    float off3 = red[5][0] + bo[3];
    const float a0 = red[12][0] + ba[0];
    const float a1 = red[13][0] + ba[1];

    const float m  = fmaxf(obj0, obj1);
    const float e0 = expf(obj0 - m), e1 = expf(obj1 - m);
    const float se = e0 + e1;
    obj_soft[r*2+0] = e0 / se;
    obj_soft[r*2+1] = e1 / se;
    orient[r] = atan2f(a1, a0);

    const float pb0 = bev_abs[r*4+0] + 0.1f*off0;
    const float pb1 = bev_abs[r*4+1] + 0.1f*off1;
    const float pb2 = bev_abs[r*4+2] + 0.1f*off2;
    const float pb3 = bev_abs[r*4+3] + 0.1f*off3;
    boxes[r*4+0] = fminf(pb0, pb2);
    boxes[r*4+1] = fminf(pb1, pb3);
    boxes[r*4+2] = fmaxf(pb0, pb2);
    boxes[r*4+3] = fmaxf(pb1, pb3);
    scores[r] = obj1;
  }
}

// ---------------- NMS stage 1: stable descending argsort (rank counting) ----------------
__global__ __launch_bounds__(128) void sort_kernel(
    const float* __restrict__ scores, const float* __restrict__ boxes,
    int* __restrict__ order, float4* __restrict__ sboxes, float* __restrict__ sarea)
{
  const int i = blockIdx.x * 128 + threadIdx.x;
  const float my = scores[i];
  int pos = 0;
  for (int j = 0; j < NBOX; ++j) {
    const float sj = scores[j];
    pos += (sj > my) || (sj == my && j < i);
  }
  const float b0 = boxes[i*4+0], b1 = boxes[i*4+1];
  const float b2 = boxes[i*4+2], b3 = boxes[i*4+3];
  order[pos]  = i;
  sboxes[pos] = make_float4(b0, b1, b2, b3);
  sarea[pos]  = fmaxf(b2 - b0, 0.0f) * fmaxf(b3 - b1, 0.0f);
}

// ---------------- NMS stage 2: triangular suppression bitmask ----------------
// Row i (sorted) stores words w = i>>6 .. 15; bit j set iff j>i && iou>thr.
__device__ __forceinline__ int tri_base(int i) {
  const int b = i >> 6;
  return 64*(16*b - (b*(b-1))/2) + (i & 63)*(16 - b);
}

__global__ __launch_bounds__(256) void maskbuild_kernel(
    const float4* __restrict__ sboxes, const float* __restrict__ sarea,
    unsigned long long* __restrict__ Mtri)
{
  __shared__ float4 sb[NBOX];
  __shared__ float  sa[NBOX];
  const int tid = threadIdx.x;
  for (int t = tid; t < NBOX; t += 256) { sb[t] = sboxes[t]; sa[t] = sarea[t]; }
  __syncthreads();
  const int wv = tid >> 6, lane = tid & 63;
  for (int r = 0; r < 4; ++r) {
    const int i = blockIdx.x * 16 + wv * 4 + r;
    const float4 bi = sb[i];
    const float  ai = sa[i];
    const int b = i >> 6;
    const int base = tri_base(i);
    for (int w = b; w < 16; ++w) {
      const int j = w * 64 + lane;
      const float4 bj = sb[j];
      const float lt0 = fmaxf(bi.x, bj.x), lt1 = fmaxf(bi.y, bj.y);
      const float rb0 = fminf(bi.z, bj.z), rb1 = fminf(bi.w, bj.w);
      const float wq = fmaxf(rb0 - lt0, 0.0f), hq = fmaxf(rb1 - lt1, 0.0f);
      const float inter = wq * hq;
      const float iou = inter / (ai + sa[j] - inter + 1e-8f);
      const unsigned long long bits = __ballot((j > i) && (iou > NMS_THR_F));
      if (lane == 0) Mtri[base + (w - b)] = bits;
    }
  }
}

// ---------------- NMS stage 3: barrier-free greedy scan + output gather ----------------
__global__ __launch_bounds__(1024) void scan_out_kernel(
    const unsigned long long* __restrict__ Mtri_g, const int* __restrict__ order,
    const float4* __restrict__ sboxes, const float* __restrict__ obj_soft,
    const float* __restrict__ orient, float* __restrict__ out)
{
  __shared__ unsigned long long M[MTRI_WORDS];
  __shared__ unsigned long long keepw[16];
  const int tid = threadIdx.x;
  for (int t = tid; t < MTRI_WORDS; t += 1024) M[t] = Mtri_g[t];
  __syncthreads();

  if (tid < 64) {
    const int lane = tid;
    unsigned long long kw = (lane < 16) ? ~0ull : 0ull;  // keep word per lane
    for (int w = 0; w < 16; ++w) {
      unsigned long long rem = __shfl(kw, w);            // kept bits of word w
      while (rem) {
        const int bpos = __builtin_ctzll(rem);
        const int i = w * 64 + bpos;                     // next kept box (sorted pos)
        const int base = tri_base(i);                    // i>>6 == w here
        unsigned long long m = 0;
        if (lane >= w && lane < 16) m = M[base + (lane - w)];
        kw &= ~m;                                        // suppress
        const unsigned long long updated = __shfl(kw, w);
        rem = (bpos == 63) ? 0ull : (updated & (~0ull << (bpos + 1)));
      }
    }
    if (lane < 16) keepw[lane] = kw;
  }
  __syncthreads();

  const int w = tid >> 6, bpos = tid & 63;
  int pre = 0, total = 0;
#pragma unroll
  for (int q = 0; q < 16; ++q) {
    const int pc = __popcll(keepw[q]);
    total += pc;
    if (q < w) pre += pc;
  }
  pre += __popcll(keepw[w] & ((bpos == 0) ? 0ull : (~0ull >> (64 - bpos))));
  const int keep_self = (int)((keepw[w] >> bpos) & 1ull);
  const int rank = keep_self ? pre : (total + tid - pre);

  if (rank < NMS_OUT) {
    const int ob = order[tid];
    const float4 bx = sboxes[tid];
    out[rank*7+0] = obj_soft[ob*2+0];
    out[rank*7+1] = obj_soft[ob*2+1];
    out[rank*7+2] = bx.x;
    out[rank*7+3] = bx.y;
    out[rank*7+4] = bx.z;
    out[rank*7+5] = bx.w;
    out[rank*7+6] = orient[ob];
  }
}

extern "C" void kernel_launch(void* const* d_in, const int* in_sizes, int n_in,
                              void* d_out, int out_size, void* d_ws, size_t ws_size,
                              hipStream_t stream) {
  (void)in_sizes; (void)n_in; (void)out_size; (void)ws_size;
  const float* img       = (const float*)d_in[0];
  const float* bev       = (const float*)d_in[1];
  const float* img_boxes = (const float*)d_in[2];
  const float* bev_boxes = (const float*)d_in[3];
  const float* bev_abs   = (const float*)d_in[4];
  const float* img_mask  = (const float*)d_in[5];
  const float* bev_mask  = (const float*)d_in[6];
  const float* W1 = (const float*)d_in[7];
  const float* b1 = (const float*)d_in[8];
  const float* W2 = (const float*)d_in[9];
  const float* b2 = (const float*)d_in[10];
  const float* Wc = (const float*)d_in[11];
  const float* bc = (const float*)d_in[12];
  const float* Wo = (const float*)d_in[13];
  const float* bo = (const float*)d_in[14];
  const float* Wa = (const float*)d_in[15];
  const float* ba = (const float*)d_in[16];
  float* out = (float*)d_out;

  float* ws = (float*)d_ws;
  float* x        = ws;                       // 1024*1568
  float* h1       = x  + (size_t)NBOX*FEAT;   // 1024*2048
  float* h2       = h1 + (size_t)NBOX*HD;     // 1024*2048
  float* obj_soft = h2 + (size_t)NBOX*HD;     // 1024*2
  float* boxesf   = obj_soft + NBOX*2;        // 1024*4
  float* orient   = boxesf + NBOX*4;          // 1024
  float* scores   = orient + NBOX;            // 1024
  int*   order    = (int*)(scores + NBOX);    // 1024 ints
  float4* sboxes  = (float4*)(order + NBOX);  // 1024 float4 (16B-aligned: offset even)
  float* sarea    = (float*)(sboxes + NBOX);  // 1024
  unsigned long long* Mtri = (unsigned long long*)(sarea + NBOX);  // 8704 u64

  roi_fuse_kernel<<<NBOX, 256, 0, stream>>>(img, bev, img_boxes, bev_boxes,
                                            img_mask, bev_mask, x);
  gemm_bias_act<1><<<dim3(HD/64, NBOX/64), 256, 0, stream>>>(x,  W1, b1, h1, NBOX, HD, FEAT);
  gemm_bias_act<1><<<dim3(HD/64, NBOX/64), 256, 0, stream>>>(h1, W2, b2, h2, NBOX, HD, HD);
  heads_kernel<<<NBOX, 256, 0, stream>>>(h2, Wc, bc, Wo, bo, Wa, ba, bev_abs,
                                         obj_soft, boxesf, orient, scores);
  sort_kernel<<<8, 128, 0, stream>>>(scores, boxesf, order, sboxes, sarea);
  maskbuild_kernel<<<64, 256, 0, stream>>>(sboxes, sarea, Mtri);
  scan_out_kernel<<<1, 1024, 0, stream>>>(Mtri, order, sboxes, obj_soft, orient, out);
}

// Round 4
// 349.113 us; speedup vs baseline: 1.7724x; 1.4175x over previous
//
#include <hip/hip_runtime.h>
#include <math.h>

#define NBOX 1024
#define ROI_N 7
#define CH 32
#define FEAT (ROI_N*ROI_N*CH)   // 1568
#define K1PAD 1600              // FEAT padded to multiple of 64
#define HD 2048
#define NMS_THR_F 0.01f
#define NMS_OUT 100
#define MTRI_WORDS 8704         // sum_{b=0..15} 64*(16-b)

typedef _Float16 f16;
typedef f16 f16x4 __attribute__((ext_vector_type(4)));
typedef f16 f16x8 __attribute__((ext_vector_type(8)));
typedef float f32x4 __attribute__((ext_vector_type(4)));

// ---------------- ROI align (both maps) + fuse (writes K1PAD-padded rows) ----------------
__global__ __launch_bounds__(256) void roi_fuse_kernel(
    const float* __restrict__ img, const float* __restrict__ bev,
    const float* __restrict__ img_boxes, const float* __restrict__ bev_boxes,
    const float* __restrict__ img_mask, const float* __restrict__ bev_mask,
    float* __restrict__ xout)
{
  const int b = blockIdx.x;
  const float mi = img_mask[0], mb = bev_mask[0];
  const float denom = mi + mb;

  const float iy0 = img_boxes[b*4+0], ix0 = img_boxes[b*4+1];
  const float iy1 = img_boxes[b*4+2], ix1 = img_boxes[b*4+3];
  const float by0 = bev_boxes[b*4+0], bx0 = bev_boxes[b*4+1];
  const float by1 = bev_boxes[b*4+2], bx1 = bev_boxes[b*4+3];

  for (int idx = threadIdx.x; idx < K1PAD; idx += 256) {
    if (idx >= FEAT) { xout[(size_t)b*K1PAD + idx] = 0.0f; continue; }
    const int ti  = idx / (ROI_N*CH);
    const int rem = idx - ti*(ROI_N*CH);
    const int tj  = rem >> 5;
    const int c   = rem & 31;
    const float tt_i = (ti == ROI_N-1) ? 1.0f : ti * (1.0f/(ROI_N-1));
    const float tt_j = (tj == ROI_N-1) ? 1.0f : tj * (1.0f/(ROI_N-1));

    float vi, vb;
    {
      const int H = 360, W = 1200;
      const float ys = (iy0 + (iy1 - iy0) * tt_i) * (float)(H-1);
      const float xs = (ix0 + (ix1 - ix0) * tt_j) * (float)(W-1);
      int y0 = (int)floorf(ys); y0 = y0 < 0 ? 0 : (y0 > H-1 ? H-1 : y0);
      int x0 = (int)floorf(xs); x0 = x0 < 0 ? 0 : (x0 > W-1 ? W-1 : x0);
      const int y1 = (y0+1 > H-1) ? H-1 : y0+1;
      const int x1 = (x0+1 > W-1) ? W-1 : x0+1;
      const float wy = ys - (float)y0;
      const float wx = xs - (float)x0;
      const float f00 = img[(y0*W + x0)*CH + c];
      const float f01 = img[(y0*W + x1)*CH + c];
      const float f10 = img[(y1*W + x0)*CH + c];
      const float f11 = img[(y1*W + x1)*CH + c];
      vi = f00*(1.0f-wy)*(1.0f-wx) + f01*(1.0f-wy)*wx
         + f10*wy*(1.0f-wx)        + f11*wy*wx;
    }
    {
      const int H = 700, W = 800;
      const float ys = (by0 + (by1 - by0) * tt_i) * (float)(H-1);
      const float xs = (bx0 + (bx1 - bx0) * tt_j) * (float)(W-1);
      int y0 = (int)floorf(ys); y0 = y0 < 0 ? 0 : (y0 > H-1 ? H-1 : y0);
      int x0 = (int)floorf(xs); x0 = x0 < 0 ? 0 : (x0 > W-1 ? W-1 : x0);
      const int y1 = (y0+1 > H-1) ? H-1 : y0+1;
      const int x1 = (x0+1 > W-1) ? W-1 : x0+1;
      const float wy = ys - (float)y0;
      const float wx = xs - (float)x0;
      const float f00 = bev[(y0*W + x0)*CH + c];
      const float f01 = bev[(y0*W + x1)*CH + c];
      const float f10 = bev[(y1*W + x0)*CH + c];
      const float f11 = bev[(y1*W + x1)*CH + c];
      vb = f00*(1.0f-wy)*(1.0f-wx) + f01*(1.0f-wy)*wx
         + f10*wy*(1.0f-wx)        + f11*wy*wx;
    }
    xout[(size_t)b*K1PAD + idx] = (mi*vi + mb*vb) / denom;
  }
}

// ---------------- transpose + f16 hi/lo split of weights: W[K][N] -> Wt[N][Kpad] ----------
__global__ __launch_bounds__(256) void convt_w_kernel(
    const float* __restrict__ W, f16* __restrict__ Wt_hi, f16* __restrict__ Wt_lo,
    int K, int Kpad, int N)
{
  __shared__ float t[32][33];
  const int tx = threadIdx.x, ty = threadIdx.y;
  const int n0 = blockIdx.x * 32, k0 = blockIdx.y * 32;
#pragma unroll
  for (int r = 0; r < 4; ++r) {
    const int k = k0 + ty*4 + r;
    t[ty*4+r][tx] = (k < K) ? W[(size_t)k*N + n0 + tx] : 0.0f;
  }
  __syncthreads();
#pragma unroll
  for (int r = 0; r < 4; ++r) {
    const int n = n0 + ty*4 + r;
    const float v = t[tx][ty*4+r];
    const f16 h = (f16)v;
    const f16 l = (f16)((v - (float)h) * 4096.0f);
    Wt_hi[(size_t)n*Kpad + k0 + tx] = h;
    Wt_lo[(size_t)n*Kpad + k0 + tx] = l;
  }
}

// ---------------- MFMA GEMM, f16 hi/lo 3-pass split, fused bias (+ReLU) ----------------
// C[M,N] = act(A[M,K](f32) @ Bt[N,K]^T + bias); tile 64x64, BK=64, 256 thr (4 waves 2x2).
#define LOADG(KK)                                                              \
  do {                                                                         \
    _Pragma("unroll")                                                          \
    for (int i_ = 0; i_ < 4; ++i_) {                                           \
      const int idx_ = i_*256 + tid;                                           \
      const int r_ = idx_ >> 4, kq_ = (idx_ & 15) * 4;                         \
      areg[i_] = *(const float4*)&A[(size_t)(m0 + r_)*K + (KK) + kq_];         \
    }                                                                          \
    _Pragma("unroll")                                                          \
    for (int i_ = 0; i_ < 2; ++i_) {                                           \
      const int idx_ = i_*256 + tid;                                           \
      const int r_ = idx_ >> 3, kq_ = (idx_ & 7) * 8;                          \
      bhreg[i_] = *(const f16x8*)&Bt_hi[(size_t)(n0 + r_)*K + (KK) + kq_];     \
      blreg[i_] = *(const f16x8*)&Bt_lo[(size_t)(n0 + r_)*K + (KK) + kq_];     \
    }                                                                          \
  } while (0)

template<int RELU>
__global__ __launch_bounds__(256) void gemm_f16x3(
    const float* __restrict__ A, const f16* __restrict__ Bt_hi,
    const f16* __restrict__ Bt_lo, const float* __restrict__ bias,
    float* __restrict__ C, int M, int N, int K)
{
  __shared__ f16 Ah[64][72], Al[64][72], Bh[64][72], Bl[64][72];
  const int tid  = threadIdx.x;
  const int m0 = blockIdx.y * 64, n0 = blockIdx.x * 64;
  const int wid = tid >> 6, lane = tid & 63;
  const int wr = wid >> 1, wc = wid & 1;
  const int frow = lane & 15, fkg = lane >> 4;

  f32x4 acc1[2][2], acc2[2][2];
#pragma unroll
  for (int i = 0; i < 2; ++i)
#pragma unroll
    for (int j = 0; j < 2; ++j)
#pragma unroll
      for (int r = 0; r < 4; ++r) { acc1[i][j][r] = 0.0f; acc2[i][j][r] = 0.0f; }

  float4 areg[4];
  f16x8 bhreg[2], blreg[2];

  LOADG(0);
  for (int k0 = 0; k0 < K; k0 += 64) {
    __syncthreads();
#pragma unroll
    for (int i = 0; i < 4; ++i) {
      const int idx = i*256 + tid;
      const int r = idx >> 4, kq = (idx & 15) * 4;
      const float4 v = areg[i];
      f16x4 hv, lv;
      { const f16 h = (f16)v.x; hv[0] = h; lv[0] = (f16)((v.x - (float)h) * 4096.0f); }
      { const f16 h = (f16)v.y; hv[1] = h; lv[1] = (f16)((v.y - (float)h) * 4096.0f); }
      { const f16 h = (f16)v.z; hv[2] = h; lv[2] = (f16)((v.z - (float)h) * 4096.0f); }
      { const f16 h = (f16)v.w; hv[3] = h; lv[3] = (f16)((v.w - (float)h) * 4096.0f); }
      *(f16x4*)&Ah[r][kq] = hv;
      *(f16x4*)&Al[r][kq] = lv;
    }
#pragma unroll
    for (int i = 0; i < 2; ++i) {
      const int idx = i*256 + tid;
      const int r = idx >> 3, kq = (idx & 7) * 8;
      *(f16x8*)&Bh[r][kq] = bhreg[i];
      *(f16x8*)&Bl[r][kq] = blreg[i];
    }
    __syncthreads();
    if (k0 + 64 < K) { LOADG(k0 + 64); }
#pragma unroll
    for (int kc = 0; kc < 2; ++kc) {
      f16x8 ah[2], al[2], bh[2], bl[2];
#pragma unroll
      for (int i = 0; i < 2; ++i) {
        ah[i] = *(const f16x8*)&Ah[wr*32 + i*16 + frow][kc*32 + fkg*8];
        al[i] = *(const f16x8*)&Al[wr*32 + i*16 + frow][kc*32 + fkg*8];
        bh[i] = *(const f16x8*)&Bh[wc*32 + i*16 + frow][kc*32 + fkg*8];
        bl[i] = *(const f16x8*)&Bl[wc*32 + i*16 + frow][kc*32 + fkg*8];
      }
#pragma unroll
      for (int i = 0; i < 2; ++i)
#pragma unroll
        for (int j = 0; j < 2; ++j) {
          acc1[i][j] = __builtin_amdgcn_mfma_f32_16x16x32_f16(ah[i], bh[j], acc1[i][j], 0, 0, 0);
          acc2[i][j] = __builtin_amdgcn_mfma_f32_16x16x32_f16(ah[i], bl[j], acc2[i][j], 0, 0, 0);
          acc2[i][j] = __builtin_amdgcn_mfma_f32_16x16x32_f16(al[i], bh[j], acc2[i][j], 0, 0, 0);
        }
    }
  }

  const float s = 1.0f / 4096.0f;
#pragma unroll
  for (int i = 0; i < 2; ++i)
#pragma unroll
    for (int j = 0; j < 2; ++j) {
      const int col = n0 + wc*32 + j*16 + frow;
      const float bv = bias[col];
#pragma unroll
      for (int r = 0; r < 4; ++r) {
        const int row = m0 + wr*32 + i*16 + fkg*4 + r;
        float v = acc1[i][j][r] + acc2[i][j][r] * s + bv;
        if (RELU) v = fmaxf(v, 0.0f);
        C[(size_t)row*N + col] = v;
      }
    }
}

// ---------------- heads ----------------
__global__ __launch_bounds__(256) void heads_kernel(
    const float* __restrict__ h,
    const float* __restrict__ Wc, const float* __restrict__ bc,
    const float* __restrict__ Wo, const float* __restrict__ bo,
    const float* __restrict__ Wa, const float* __restrict__ ba,
    const float* __restrict__ bev_abs,
    float* __restrict__ obj_soft, float* __restrict__ boxes,
    float* __restrict__ orient, float* __restrict__ scores)
{
  const int r = blockIdx.x;
  const int tid = threadIdx.x;
  float acc[14];
#pragma unroll
  for (int j = 0; j < 14; ++j) acc[j] = 0.0f;
  for (int k = tid; k < HD; k += 256) {
    const float hv = h[(size_t)r*HD + k];
    acc[0]  += hv * Wc[k*2+0];
    acc[1]  += hv * Wc[k*2+1];
#pragma unroll
    for (int j = 0; j < 10; ++j) acc[2+j] += hv * Wo[k*10+j];
    acc[12] += hv * Wa[k*2+0];
    acc[13] += hv * Wa[k*2+1];
  }
  __shared__ float red[14][256];
#pragma unroll
  for (int j = 0; j < 14; ++j) red[j][tid] = acc[j];
  __syncthreads();
  for (int s = 128; s > 0; s >>= 1) {
    if (tid < s) {
#pragma unroll
      for (int j = 0; j < 14; ++j) red[j][tid] += red[j][tid + s];
    }
    __syncthreads();
  }
  if (tid == 0) {
    const float obj0 = red[0][0] + bc[0];
    const float obj1 = red[1][0] + bc[1];
    float off0 = red[2][0] + bo[0];
    float off1 = red[3][0] + bo[1];
    float off2 = red[4][0] + bo[2];
    float off3 = red[5][0] + bo[3];
    const float a0 = red[12][0] + ba[0];
    const float a1 = red[13][0] + ba[1];

    const float m  = fmaxf(obj0, obj1);
    const float e0 = expf(obj0 - m), e1 = expf(obj1 - m);
    const float se = e0 + e1;
    obj_soft[r*2+0] = e0 / se;
    obj_soft[r*2+1] = e1 / se;
    orient[r] = atan2f(a1, a0);

    const float pb0 = bev_abs[r*4+0] + 0.1f*off0;
    const float pb1 = bev_abs[r*4+1] + 0.1f*off1;
    const float pb2 = bev_abs[r*4+2] + 0.1f*off2;
    const float pb3 = bev_abs[r*4+3] + 0.1f*off3;
    boxes[r*4+0] = fminf(pb0, pb2);
    boxes[r*4+1] = fminf(pb1, pb3);
    boxes[r*4+2] = fmaxf(pb0, pb2);
    boxes[r*4+3] = fmaxf(pb1, pb3);
    scores[r] = obj1;
  }
}

// ---------------- NMS stage 1: stable descending argsort (rank counting) ----------------
__global__ __launch_bounds__(128) void sort_kernel(
    const float* __restrict__ scores, const float* __restrict__ boxes,
    int* __restrict__ order, float4* __restrict__ sboxes, float* __restrict__ sarea)
{
  const int i = blockIdx.x * 128 + threadIdx.x;
  const float my = scores[i];
  int pos = 0;
  for (int j = 0; j < NBOX; ++j) {
    const float sj = scores[j];
    pos += (sj > my) || (sj == my && j < i);
  }
  const float b0 = boxes[i*4+0], b1 = boxes[i*4+1];
  const float b2 = boxes[i*4+2], b3 = boxes[i*4+3];
  order[pos]  = i;
  sboxes[pos] = make_float4(b0, b1, b2, b3);
  sarea[pos]  = fmaxf(b2 - b0, 0.0f) * fmaxf(b3 - b1, 0.0f);
}

// ---------------- NMS stage 2: triangular suppression bitmask ----------------
__device__ __forceinline__ int tri_base(int i) {
  const int b = i >> 6;
  return 64*(16*b - (b*(b-1))/2) + (i & 63)*(16 - b);
}

__global__ __launch_bounds__(256) void maskbuild_kernel(
    const float4* __restrict__ sboxes, const float* __restrict__ sarea,
    unsigned long long* __restrict__ Mtri)
{
  __shared__ float4 sb[NBOX];
  __shared__ float  sa[NBOX];
  const int tid = threadIdx.x;
  for (int t = tid; t < NBOX; t += 256) { sb[t] = sboxes[t]; sa[t] = sarea[t]; }
  __syncthreads();
  const int wv = tid >> 6, lane = tid & 63;
  for (int r = 0; r < 4; ++r) {
    const int i = blockIdx.x * 16 + wv * 4 + r;
    const float4 bi = sb[i];
    const float  ai = sa[i];
    const int b = i >> 6;
    const int base = tri_base(i);
    for (int w = b; w < 16; ++w) {
      const int j = w * 64 + lane;
      const float4 bj = sb[j];
      const float lt0 = fmaxf(bi.x, bj.x), lt1 = fmaxf(bi.y, bj.y);
      const float rb0 = fminf(bi.z, bj.z), rb1 = fminf(bi.w, bj.w);
      const float wq = fmaxf(rb0 - lt0, 0.0f), hq = fmaxf(rb1 - lt1, 0.0f);
      const float inter = wq * hq;
      const float iou = inter / (ai + sa[j] - inter + 1e-8f);
      const unsigned long long bits = __ballot((j > i) && (iou > NMS_THR_F));
      if (lane == 0) Mtri[base + (w - b)] = bits;
    }
  }
}

// ---------------- NMS stage 3: barrier-free greedy scan + output gather ----------------
__global__ __launch_bounds__(1024) void scan_out_kernel(
    const unsigned long long* __restrict__ Mtri_g, const int* __restrict__ order,
    const float4* __restrict__ sboxes, const float* __restrict__ obj_soft,
    const float* __restrict__ orient, float* __restrict__ out)
{
  __shared__ unsigned long long M[MTRI_WORDS];
  __shared__ unsigned long long keepw[16];
  const int tid = threadIdx.x;
  for (int t = tid; t < MTRI_WORDS; t += 1024) M[t] = Mtri_g[t];
  __syncthreads();

  if (tid < 64) {
    const int lane = tid;
    unsigned long long kw = (lane < 16) ? ~0ull : 0ull;
    for (int w = 0; w < 16; ++w) {
      unsigned long long rem = __shfl(kw, w);
      while (rem) {
        const int bpos = __builtin_ctzll(rem);
        const int i = w * 64 + bpos;
        const int base = tri_base(i);
        unsigned long long m = 0;
        if (lane >= w && lane < 16) m = M[base + (lane - w)];
        kw &= ~m;
        const unsigned long long updated = __shfl(kw, w);
        rem = (bpos == 63) ? 0ull : (updated & (~0ull << (bpos + 1)));
      }
    }
    if (lane < 16) keepw[lane] = kw;
  }
  __syncthreads();

  const int w = tid >> 6, bpos = tid & 63;
  int pre = 0, total = 0;
#pragma unroll
  for (int q = 0; q < 16; ++q) {
    const int pc = __popcll(keepw[q]);
    total += pc;
    if (q < w) pre += pc;
  }
  pre += __popcll(keepw[w] & ((bpos == 0) ? 0ull : (~0ull >> (64 - bpos))));
  const int keep_self = (int)((keepw[w] >> bpos) & 1ull);
  const int rank = keep_self ? pre : (total + tid - pre);

  if (rank < NMS_OUT) {
    const int ob = order[tid];
    const float4 bx = sboxes[tid];
    out[rank*7+0] = obj_soft[ob*2+0];
    out[rank*7+1] = obj_soft[ob*2+1];
    out[rank*7+2] = bx.x;
    out[rank*7+3] = bx.y;
    out[rank*7+4] = bx.z;
    out[rank*7+5] = bx.w;
    out[rank*7+6] = orient[ob];
  }
}

extern "C" void kernel_launch(void* const* d_in, const int* in_sizes, int n_in,
                              void* d_out, int out_size, void* d_ws, size_t ws_size,
                              hipStream_t stream) {
  (void)in_sizes; (void)n_in; (void)out_size; (void)ws_size;
  const float* img       = (const float*)d_in[0];
  const float* bev       = (const float*)d_in[1];
  const float* img_boxes = (const float*)d_in[2];
  const float* bev_boxes = (const float*)d_in[3];
  const float* bev_abs   = (const float*)d_in[4];
  const float* img_mask  = (const float*)d_in[5];
  const float* bev_mask  = (const float*)d_in[6];
  const float* W1 = (const float*)d_in[7];
  const float* b1 = (const float*)d_in[8];
  const float* W2 = (const float*)d_in[9];
  const float* b2 = (const float*)d_in[10];
  const float* Wc = (const float*)d_in[11];
  const float* bc = (const float*)d_in[12];
  const float* Wo = (const float*)d_in[13];
  const float* bo = (const float*)d_in[14];
  const float* Wa = (const float*)d_in[15];
  const float* ba = (const float*)d_in[16];
  float* out = (float*)d_out;

  float* ws = (float*)d_ws;
  float* x        = ws;                       // 1024*1600 f32 (padded)
  float* h1       = x  + (size_t)NBOX*K1PAD;  // 1024*2048
  float* h2       = h1 + (size_t)NBOX*HD;     // 1024*2048
  f16*  Wt1_hi    = (f16*)(h2 + (size_t)NBOX*HD);          // 2048*1600 f16
  f16*  Wt1_lo    = Wt1_hi + (size_t)HD*K1PAD;
  f16*  Wt2_hi    = Wt1_lo + (size_t)HD*K1PAD;             // 2048*2048 f16
  f16*  Wt2_lo    = Wt2_hi + (size_t)HD*HD;
  float* obj_soft = (float*)(Wt2_lo + (size_t)HD*HD);      // 1024*2
  float* boxesf   = obj_soft + NBOX*2;
  float* orient   = boxesf + NBOX*4;
  float* scores   = orient + NBOX;
  int*   order    = (int*)(scores + NBOX);
  float4* sboxes  = (float4*)(order + NBOX);
  float* sarea    = (float*)(sboxes + NBOX);
  unsigned long long* Mtri = (unsigned long long*)(sarea + NBOX);

  roi_fuse_kernel<<<NBOX, 256, 0, stream>>>(img, bev, img_boxes, bev_boxes,
                                            img_mask, bev_mask, x);
  convt_w_kernel<<<dim3(HD/32, K1PAD/32), dim3(32,8), 0, stream>>>(W1, Wt1_hi, Wt1_lo, FEAT, K1PAD, HD);
  convt_w_kernel<<<dim3(HD/32, HD/32),    dim3(32,8), 0, stream>>>(W2, Wt2_hi, Wt2_lo, HD, HD, HD);
  gemm_f16x3<1><<<dim3(HD/64, NBOX/64), 256, 0, stream>>>(x,  Wt1_hi, Wt1_lo, b1, h1, NBOX, HD, K1PAD);
  gemm_f16x3<1><<<dim3(HD/64, NBOX/64), 256, 0, stream>>>(h1, Wt2_hi, Wt2_lo, b2, h2, NBOX, HD, HD);
  heads_kernel<<<NBOX, 256, 0, stream>>>(h2, Wc, bc, Wo, bo, Wa, ba, bev_abs,
                                         obj_soft, boxesf, orient, scores);
  sort_kernel<<<8, 128, 0, stream>>>(scores, boxesf, order, sboxes, sarea);
  maskbuild_kernel<<<64, 256, 0, stream>>>(sboxes, sarea, Mtri);
  scan_out_kernel<<<1, 1024, 0, stream>>>(Mtri, order, sboxes, obj_soft, orient, out);
}